// Round 16
// baseline (601.971 us; speedup 1.0000x reference)
//
#include <hip/hip_runtime.h>
#include <hip/hip_fp16.h>
#include <math.h>

#define S_TOK 8192
#define DMODEL 1024
#define HDIM 4096
#define NEXP 8
#define KTOP2 2
#define CAP 2560
#define SK (S_TOK*KTOP2)

typedef _Float16 f16;
typedef _Float16 f16x8 __attribute__((ext_vector_type(8)));
typedef float f32x4 __attribute__((ext_vector_type(4)));

typedef const __attribute__((address_space(1))) void* gas_cp;
typedef __attribute__((address_space(3))) void* las_p;

__device__ __forceinline__ void gload16(const void* g, void* l) {
  __builtin_amdgcn_global_load_lds((gas_cp)g, (las_p)l, 16, 0, 0);
}

// ---------------- ws layout (bytes) ----------------
static const size_t ZERO_OFF  = 0;          // 4096 zeroed every call
static const size_t IMP_OFF   = 4096;
static const size_t CNT_OFF   = 4160;
static const size_t NSEL_OFF  = 4224;
static const size_t PROBS_OFF = 8192;
static const size_t TOPKI_OFF = 270336;
static const size_t TOPKV_OFF = 335872;
static const size_t LISTT_OFF = 401408;
static const size_t LISTW_OFF = 663552;
static const size_t LISTF_OFF = 925696;     // dead after select -> reused for tokmap
static const size_t SELT_OFF  = 1187840;
static const size_t SELW_OFF  = 1269760;
static const size_t XF16_OFF  = 1351680;                                  // S*D f16 = 16MB
static const size_t W1TA_OFF  = 18128896;                                 // 8*H*D f16 = 64MB
static const size_t W2TA_OFF  = W1TA_OFF + (size_t)NEXP*HDIM*DMODEL*2;
static const size_t HA_OFF    = W2TA_OFF + (size_t)NEXP*DMODEL*HDIM*2;    // 8*CAP*H f16 = 160MB
static const size_t YE_OFF    = XF16_OFF;   // 40MB aliased over xf16/w1t (dead by gemm2)
static const size_t TOKMAP_OFF = LISTF_OFF;

// ---------------- fast erf-based gelu (A&S 7.1.26, |err|<1.5e-7) ----------------
__device__ __forceinline__ float fast_gelu(float v) {
  float av = fabsf(v);
  float z  = av * 0.70710678118654752f;
  float tt = __builtin_amdgcn_rcpf(1.0f + 0.3275911f*z);
  float poly = tt*(0.254829592f + tt*(-0.284496736f + tt*(1.421413741f + tt*(-1.453152027f + tt*1.061405429f))));
  float ee = 1.0f - poly*__expf(-z*z);       // erf(z) for z>=0
  return 0.5f*(v + v*copysignf(ee, v));      // 0.5*v*(1+erf(v/sqrt2))
}

// ---------------- gate (fused: also emits x as f16) ----------------
__global__ __launch_bounds__(256) void gate_kernel(const float* __restrict__ x, const float* __restrict__ Wg,
                                                   float* __restrict__ probs, int* __restrict__ tki,
                                                   float* __restrict__ tkv, f16* __restrict__ xf) {
  int lane = threadIdx.x & 63;
  int t = blockIdx.x*4 + (threadIdx.x >> 6);
  const float* xr = x + (size_t)t*DMODEL;
  f16* xw = xf + (size_t)t*DMODEL;
  float p[NEXP];
  #pragma unroll
  for (int e=0;e<NEXP;e++) p[e] = 0.f;
  #pragma unroll
  for (int it=0; it<4; ++it) {
    int d0 = it*256 + lane*4;
    float4 xv = *(const float4*)(xr + d0);
    union { f16 h[4]; short4 s4; } o;
    o.h[0]=(f16)xv.x; o.h[1]=(f16)xv.y; o.h[2]=(f16)xv.z; o.h[3]=(f16)xv.w;
    *(short4*)(xw + d0) = o.s4;
    #pragma unroll
    for (int c=0;c<4;c++) {
      float xs = (c==0)?xv.x:(c==1)?xv.y:(c==2)?xv.z:xv.w;
      const float4* wg = (const float4*)(Wg + (size_t)(d0+c)*NEXP);
      float4 w0 = wg[0], w1 = wg[1];
      p[0]+=xs*w0.x; p[1]+=xs*w0.y; p[2]+=xs*w0.z; p[3]+=xs*w0.w;
      p[4]+=xs*w1.x; p[5]+=xs*w1.y; p[6]+=xs*w1.z; p[7]+=xs*w1.w;
    }
  }
  #pragma unroll
  for (int off=32; off; off>>=1) {
    #pragma unroll
    for (int e=0;e<NEXP;e++) p[e] += __shfl_xor(p[e], off);
  }
  float mx = p[0];
  #pragma unroll
  for (int e=1;e<NEXP;e++) mx = fmaxf(mx, p[e]);
  float sum = 0.f;
  #pragma unroll
  for (int e=0;e<NEXP;e++) { p[e] = expf(p[e]-mx); sum += p[e]; }
  float inv = 1.f/sum;
  #pragma unroll
  for (int e=0;e<NEXP;e++) p[e] *= inv;
  if (lane == 0) {
    ((float4*)(probs + t*NEXP))[0] = make_float4(p[0],p[1],p[2],p[3]);
    ((float4*)(probs + t*NEXP))[1] = make_float4(p[4],p[5],p[6],p[7]);
    int i1 = 0; float v1 = p[0];
    #pragma unroll
    for (int e=1;e<NEXP;e++) if (p[e] > v1) { v1 = p[e]; i1 = e; }
    int i2 = -1; float v2 = -1.f;
    #pragma unroll
    for (int e=0;e<NEXP;e++) if (e != i1 && p[e] > v2) { v2 = p[e]; i2 = e; }
    tki[t*2] = i1; tki[t*2+1] = i2;
    tkv[t*2] = v1; tkv[t*2+1] = v2;
  }
}

// ---------------- importance ----------------
__global__ __launch_bounds__(256) void imp_kernel(const float* __restrict__ probs, float* __restrict__ imp) {
  int e = blockIdx.x;
  float s = 0.f;
  for (int t = threadIdx.x; t < S_TOK; t += 256) s += probs[t*NEXP + e];
  #pragma unroll
  for (int off=32; off; off>>=1) s += __shfl_xor(s, off);
  __shared__ float red[4];
  if ((threadIdx.x & 63) == 0) red[threadIdx.x>>6] = s;
  __syncthreads();
  if (threadIdx.x == 0) imp[e] = red[0]+red[1]+red[2]+red[3];
}

// ---------------- compact (+ tokmap init) ----------------
__global__ __launch_bounds__(256) void compact_kernel(const int* __restrict__ tki, const float* __restrict__ tkv,
                                                      int* __restrict__ cnt, int* __restrict__ listt,
                                                      float* __restrict__ listw, int* __restrict__ listf,
                                                      int* __restrict__ tokmap) {
  int i = blockIdx.x*256 + threadIdx.x;
  tokmap[i] = -1;
  int e = tki[i];
  int p = atomicAdd(&cnt[e], 1);
  listt[e*S_TOK + p] = i >> 1;
  listw[e*S_TOK + p] = tkv[i];
  listf[e*S_TOK + p] = i;
}

// ---------------- capacity selection (+ fused aux-loss) ----------------
__global__ __launch_bounds__(1024) void select_kernel(const int* __restrict__ listt, const float* __restrict__ listw,
                                                      const int* __restrict__ listf, const int* __restrict__ cnt,
                                                      int* __restrict__ selt, float* __restrict__ selw,
                                                      int* __restrict__ nsel, const float* __restrict__ imp,
                                                      float* __restrict__ aux_out) {
  __shared__ float kw[8192];
  __shared__ unsigned short kf[8192];
  int e = blockIdx.x;
  int n = cnt[e];
  const int* lt = listt + e*S_TOK; const float* lw = listw + e*S_TOK; const int* lf = listf + e*S_TOK;
  int* st = selt + e*CAP; float* sw = selw + e*CAP;
  if (threadIdx.x == 0) nsel[e] = (n < CAP) ? n : CAP;
  if (e == 0 && threadIdx.x == 1) {
    float a = 0.f;
    #pragma unroll
    for (int q=0;q<NEXP;q++) a += imp[q] * (float)cnt[q];
    *aux_out = a * (8.0f / 67108864.0f);
  }
  if (n <= CAP) {
    for (int i = threadIdx.x; i < CAP; i += 1024) {
      if (i < n) { st[i] = lt[i]; sw[i] = lw[i]; }
      else       { st[i] = -1;    sw[i] = 0.f;  }
    }
  } else {
    for (int i = threadIdx.x; i < n; i += 1024) { kw[i] = lw[i]; kf[i] = (unsigned short)lf[i]; }
    __syncthreads();
    for (int i = threadIdx.x; i < n; i += 1024) {
      float wi = kw[i]; int fi = kf[i];
      int rank = 0;
      for (int j = 0; j < n; ++j) {
        float wj = kw[j];
        rank += (wj > wi) || (wj == wi && (int)kf[j] < fi);
      }
      if (rank < CAP) { st[rank] = lt[i]; sw[rank] = wi; }
    }
  }
}

// ---------------- tokmap ----------------
__global__ __launch_bounds__(256) void buildmap_kernel(const int* __restrict__ selt, const int* __restrict__ tki,
                                                       int* __restrict__ tokmap) {
  int i = blockIdx.x*256 + threadIdx.x;
  int t = selt[i];
  if (t >= 0) {
    int e = i / CAP;
    int k = (tki[2*t] == e) ? 0 : 1;
    tokmap[2*t + k] = i;
  }
}

// ---------------- combine ----------------
__global__ __launch_bounds__(256) void combine2_kernel(const f16* __restrict__ ye, const int* __restrict__ tokmap,
                                                       float* __restrict__ out) {
  int t = blockIdx.x;
  int c = threadIdx.x * 4;
  int i0 = tokmap[2*t], i1 = tokmap[2*t+1];
  float4 o = {0.f, 0.f, 0.f, 0.f};
  if (i0 >= 0) {
    union { short4 s; f16 h[4]; } v;
    v.s = *(const short4*)(ye + (size_t)i0*DMODEL + c);
    o.x += (float)v.h[0]; o.y += (float)v.h[1]; o.z += (float)v.h[2]; o.w += (float)v.h[3];
  }
  if (i1 >= 0) {
    union { short4 s; f16 h[4]; } v;
    v.s = *(const short4*)(ye + (size_t)i1*DMODEL + c);
    o.x += (float)v.h[0]; o.y += (float)v.h[1]; o.z += (float)v.h[2]; o.w += (float)v.h[3];
  }
  *(float4*)(out + (size_t)t*DMODEL + c) = o;
}

// ---------------- transpose + cvt, 64x64 tiles ----------------
__global__ __launch_bounds__(256) void tcvt64_kernel(const float* __restrict__ src0, f16* __restrict__ dst0,
                                                     int R, int C) {
  __shared__ float tile[64][65];
  const float* src = src0 + (size_t)blockIdx.z*R*C;
  f16* dst = dst0 + (size_t)blockIdx.z*R*C;
  int c0 = blockIdx.x*64, r0 = blockIdx.y*64;
  int tr = threadIdx.x >> 4;
  int tc = threadIdx.x & 15;
  #pragma unroll
  for (int j=0;j<4;j++) {
    int r = tr + 16*j;
    float4 v = *(const float4*)(src + (size_t)(r0+r)*C + c0 + tc*4);
    tile[r][tc*4+0]=v.x; tile[r][tc*4+1]=v.y; tile[r][tc*4+2]=v.z; tile[r][tc*4+3]=v.w;
  }
  __syncthreads();
  #pragma unroll
  for (int j=0;j<4;j++) {
    int c = tr + 16*j;
    union { f16 h[4]; short4 s; } o;
    #pragma unroll
    for (int i=0;i<4;i++) o.h[i] = (f16)tile[tc*4+i][c];
    *(short4*)(dst + (size_t)(c0+c)*R + r0 + tc*4) = o.s;
  }
}

#define BAR()   asm volatile("s_barrier" ::: "memory")
#define VMW(n)  asm volatile("s_waitcnt vmcnt(" #n ")" ::: "memory")
#define LGKM0() asm volatile("s_waitcnt lgkmcnt(0)" ::: "memory")
#define LGKM8() asm volatile("s_waitcnt lgkmcnt(8)" ::: "memory")
#define PRIO1() __builtin_amdgcn_s_setprio(1)
#define PRIO0() __builtin_amdgcn_s_setprio(0)

// ================= GEMM1: 4-wave fat-tile 256x256, BK=64 (r16) =================
// LDS-amplification fix: 4 waves (2x2) x 128x128 wave tile -> per-K-tile LDS
// reads = 4x(128+128) rows = 128KB/CU vs 8-wave's 192KB (all r9-r14 variants
// shared the 8-wave 2x4 split and plateaued at ~27% MfmaUtil; ds_read BW was
// the invariant critical path). acc 8x8 f32x4 = 256 regs + frags 64 + addr
// ~= 370 < 450 no-spill line at 1 wave/SIMD (launch_bounds(256,1)).
// Schedule: 2-deep tile prefetch; per K-tile {VMW(16) (completes exactly tile
// j; tile j+1's 16 loads stay in flight - T4), BAR, [RD ks0 | 64 MFMA | RD ks1
// | 64 MFMA] compiler-interleaved via lgkm deps (no intra-phase barrier -> ILP
// hides ds_read latency), BAR, stage tile j+2}. Stage-after-read-barrier is
// race-free (all reads MFMA-consumed before BAR). 8-slot XOR swizzle family
// (0-conflict, r6/r7/r10-verified); linear gload dest + pre-swizzled source.
__global__ __launch_bounds__(256, 1) void gemm1_4w(const f16* __restrict__ xf, const f16* __restrict__ w1t_all,
                                                   const int* __restrict__ selt_all, const int* __restrict__ nsel_all,
                                                   f16* __restrict__ hbuf_all, const char* __restrict__ zbuf) {
  int bid = blockIdx.x;
  int wid = (bid & 7)*160 + (bid >> 3);      // XCD = expert
  int e = wid / 160; int rem = wid % 160;    // 160 = 8 supercols x (10 m x 2 n)
  int sc = rem / 20;
  int lm = (rem % 20) >> 1, ln = rem & 1;
  int m0 = lm * 256;
  int n0 = (sc*2 + ln) * 256;
  int nsel = nsel_all[e];
  if (m0 >= nsel) return;
  const int* selt = selt_all + e*CAP;
  const f16* w1t = w1t_all + (size_t)e*HDIM*DMODEL;
  f16* hbuf = hbuf_all + (size_t)e*CAP*HDIM;

  __shared__ __align__(16) char lds[131072];
  char* ldsA = lds;            // 2 x 32KB (256 rows x 128B)
  char* ldsB = lds + 65536;    // 2 x 32KB

  int tid = threadIdx.x;
  int l = tid & 63, w = tid >> 6;
  int wr = w >> 1, wc = w & 1;        // 2M x 2N waves, 128x128 each
  int fr = l & 15, kq = l >> 4;

  // staging: 8 regions of 32 rows per operand; thread -> row rg*32+(tid>>3),
  // logical slot (tid&7) pre-swizzled by row&7 (both-sides rule)
  int srow = tid >> 3;                 // 0..31
  int sswz = ((tid & 7) ^ (srow & 7)) * 16;
  const char* sA[8];
  #pragma unroll
  for (int rg=0; rg<8; rg++) {
    int t0 = selt[m0 + rg*32 + srow];
    sA[rg] = ((t0>=0) ? (const char*)(xf + (size_t)t0*DMODEL) : zbuf) + sswz;
  }
  const char* sB0 = (const char*)(w1t + (size_t)(n0 + srow)*DMODEL) + sswz;

  #define STG1(buf, t) { \
    _Pragma("unroll") for (int rg=0; rg<8; rg++) \
      gload16(sA[rg] + (t)*128, ldsA + (buf)*32768 + rg*4096 + tid*16); \
    _Pragma("unroll") for (int rg=0; rg<8; rg++) \
      gload16(sB0 + rg*65536 + (t)*128, ldsB + (buf)*32768 + rg*4096 + tid*16); }

  int slotk0 = ((kq)   ^ (fr&7))*16;
  int slotk1 = ((4+kq) ^ (fr&7))*16;
  int aoffm[8], boffn[8];
  #pragma unroll
  for (int m=0;m<8;m++) aoffm[m] = (wr*128 + m*16 + fr)*128;
  #pragma unroll
  for (int n=0;n<8;n++) boffn[n] = (wc*128 + n*16 + fr)*128;

  f16x8 aR[8], bR[8];
  f32x4 acc[8][8];
  #pragma unroll
  for (int m=0;m<8;m++)
    #pragma unroll
    for (int n=0;n<8;n++) acc[m][n] = (f32x4){0.f,0.f,0.f,0.f};

  #define RDK(buf, sk) { \
    _Pragma("unroll") for (int mm=0;mm<8;mm++) aR[mm] = *(const f16x8*)(ldsA + (buf)*32768 + aoffm[mm] + (sk)); \
    _Pragma("unroll") for (int nn=0;nn<8;nn++) bR[nn] = *(const f16x8*)(ldsB + (buf)*32768 + boffn[nn] + (sk)); }
  #define MMK() { \
    _Pragma("unroll") for (int mm=0;mm<8;mm++) \
      _Pragma("unroll") for (int nn=0;nn<8;nn++) \
        acc[mm][nn] = __builtin_amdgcn_mfma_f32_16x16x32_f16(aR[mm], bR[nn], acc[mm][nn], 0,0,0); }

  const int NT = DMODEL/64;   // 16 K-tiles
  STG1(0, 0);
  STG1(1, 1);
  for (int j = 0; j < NT; ++j) {
    int buf = j & 1;
    if (j + 1 < NT) { VMW(16); } else { VMW(0); }
    BAR();
    RDK(buf, slotk0); PRIO1(); MMK(); PRIO0();
    RDK(buf, slotk1); PRIO1(); MMK(); PRIO0();
    BAR();
    if (j + 2 < NT) STG1(buf, j+2);
  }
  #undef STG1
  #undef RDK
  #undef MMK

  int rowb = m0 + wr*128;
  int colb = n0 + wc*128;
  #pragma unroll
  for (int m=0;m<8;m++) {
    #pragma unroll
    for (int n=0;n<8;n++) {
      #pragma unroll
      for (int r=0;r<4;r++) {
        int row = rowb + m*16 + kq*4 + r;
        int col = colb + n*16 + fr;
        hbuf[(size_t)row*HDIM + col] = (f16)fast_gelu(acc[m][n][r]);
      }
    }
  }
}

// ================= GEMM2: 8-phase-family 256x128, BK=64, K=4096 (r13, proven) =================
__global__ __launch_bounds__(512, 2) void gemm2_8p(const f16* __restrict__ hbuf_all, const f16* __restrict__ w2t_all,
                                                   const float* __restrict__ selw_all, const int* __restrict__ nsel_all,
                                                   f16* __restrict__ ye) {
  int bid = blockIdx.x;
  int wid = (bid & 7)*80 + (bid >> 3);       // XCD = expert; 80 = 10m x 8n
  int e = wid / 80; int rem = wid % 80;
  int lm = rem >> 3, ln = rem & 7;
  int m0 = lm * 256;
  int n0 = ln * 128;
  int nsel = nsel_all[e];
  if (m0 >= nsel) return;
  const f16* hb  = hbuf_all + (size_t)e*CAP*HDIM;
  const f16* w2t = w2t_all + (size_t)e*DMODEL*HDIM;

  __shared__ __align__(16) char lds[98304];
  char* ldsA = lds;            // 2 x 32KB
  char* ldsB = lds + 65536;    // 2 x 16KB

  int tid = threadIdx.x;
  int l = tid & 63, w = tid >> 6;
  int wr = w >> 2, wc = w & 3;
  int fr = l & 15, kq = l >> 4;

  int srow = tid >> 3;
  int sswz = ((tid & 7) ^ (srow & 7)) * 16;
  const char* sA[2][2];
  const char* sB[2];
  #pragma unroll
  for (int h=0;h<2;h++)
    #pragma unroll
    for (int s=0;s<2;s++)
      sA[h][s] = (const char*)(hb + (size_t)(m0 + h*128 + s*64 + srow)*HDIM) + sswz;
  #pragma unroll
  for (int s=0;s<2;s++)
    sB[s] = (const char*)(w2t + (size_t)(n0 + s*64 + srow)*HDIM) + sswz;
  int dst = tid*16;

  #define STG2_A(buf,h,s,t) gload16(sA[h][s] + (t)*128, ldsA + (buf)*32768 + (h)*16384 + (s)*8192 + dst)
  #define STG2_B(buf,s,t)   gload16(sB[s] + (t)*128, ldsB + (buf)*16384 + (s)*8192 + dst)

  int slotk0 = ((kq)   ^ (fr&7))*16;
  int slotk1 = ((4+kq) ^ (fr&7))*16;
  int aBase = wr*16384 + fr*128;
  int bBase = (wc>>1)*8192 + ((wc&1)*32 + fr)*128;

  f16x8 aR[4][2], bF[2][2];
  f32x4 acc[8][2];
  #pragma unroll
  for (int m=0;m<8;m++)
    #pragma unroll
    for (int n=0;n<2;n++) acc[m][n] = (f32x4){0.f,0.f,0.f,0.f};

  #define RD2_A(buf, mq) { \
    _Pragma("unroll") for (int mm=0;mm<4;mm++) { \
      aR[mm][0] = *(const f16x8*)(ldsA + (buf)*32768 + aBase + ((mq)*4+mm)*2048 + slotk0); \
      aR[mm][1] = *(const f16x8*)(ldsA + (buf)*32768 + aBase + ((mq)*4+mm)*2048 + slotk1); } }
  #define RD2_B(buf) { \
    _Pragma("unroll") for (int nn=0;nn<2;nn++) { \
      bF[nn][0] = *(const f16x8*)(ldsB + (buf)*16384 + bBase + nn*2048 + slotk0); \
      bF[nn][1] = *(const f16x8*)(ldsB + (buf)*16384 + bBase + nn*2048 + slotk1); } }
  #define MM2(mq) { \
    _Pragma("unroll") for (int ks=0;ks<2;ks++) \
      _Pragma("unroll") for (int mm=0;mm<4;mm++) \
        _Pragma("unroll") for (int nn=0;nn<2;nn++) \
          acc[(mq)*4+mm][nn] = __builtin_amdgcn_mfma_f32_16x16x32_f16(aR[mm][ks], bF[nn][ks], acc[(mq)*4+mm][nn], 0,0,0); }

  STG2_A(0,0,0,0); STG2_A(0,0,1,0); STG2_A(0,1,0,0); STG2_A(0,1,1,0);
  STG2_B(0,0,0); STG2_B(0,1,0);
  STG2_A(1,0,0,1); STG2_A(1,1,0,1);
  STG2_B(1,0,1); STG2_B(1,1,1);
  VMW(4); BAR();

  const int NT = HDIM/64;   // 64 K-tiles, 32 iters
  for (int j = 0; j < NT/2; ++j) {
    int t1 = 2*j+1, st0 = 2*j+2, st1 = 2*j+3;
    int g0 = (st0 < NT), g1 = (st1 < NT);
    RD2_A(0,0); RD2_B(0);
    STG2_A(1,0,1,t1); STG2_A(1,1,1,t1);
    LGKM8();
    BAR(); LGKM0(); PRIO1(); MM2(0); PRIO0(); BAR();
    RD2_A(0,1);
    if (g0) { STG2_A(0,0,0,st0); STG2_A(0,1,0,st0); STG2_B(0,0,st0); STG2_B(0,1,st0); }
    BAR(); LGKM0(); PRIO1(); MM2(1); PRIO0();
    if (g0) { VMW(4); } else { VMW(0); }
    BAR();
    RD2_A(1,0); RD2_B(1);
    if (g0) { STG2_A(0,0,1,st0); STG2_A(0,1,1,st0); }
    LGKM8();
    BAR(); LGKM0(); PRIO1(); MM2(0); PRIO0(); BAR();
    RD2_A(1,1);
    if (g1) { STG2_A(1,0,0,st1); STG2_A(1,1,0,st1); STG2_B(1,0,st1); STG2_B(1,1,st1); }
    BAR(); LGKM0(); PRIO1(); MM2(1); PRIO0();
    if (g1) { VMW(4); } else { VMW(0); }
    BAR();
  }
  #undef STG2_A
  #undef STG2_B
  #undef RD2_A
  #undef RD2_B
  #undef MM2

  int rowb = m0 + wr*128;
  int colb = n0 + wc*32;
  #pragma unroll
  for (int m=0;m<8;m++) {
    #pragma unroll
    for (int r=0;r<4;r++) {
      int row = rowb + m*16 + kq*4 + r;
      float wg = selw_all[e*CAP + row];
      f16* yr = ye + (size_t)(e*CAP + row)*DMODEL;
      #pragma unroll
      for (int n=0;n<2;n++) {
        int col = colb + n*16 + fr;
        yr[col] = (f16)(acc[m][n][r] * wg);
      }
    }
  }
}

// ---------------- launch ----------------
extern "C" void kernel_launch(void* const* d_in, const int* in_sizes, int n_in,
                              void* d_out, int out_size, void* d_ws, size_t ws_size,
                              hipStream_t stream) {
  const float* x  = (const float*)d_in[0];
  const float* Wg = (const float*)d_in[1];
  const float* W1 = (const float*)d_in[2];
  const float* W2 = (const float*)d_in[3];
  float* out = (float*)d_out;

  char* ws = (char*)d_ws;
  f16*   xf16  = (f16*)(ws + XF16_OFF);
  float* probs = (float*)(ws + PROBS_OFF);
  int*   tki   = (int*)(ws + TOPKI_OFF);
  float* tkv   = (float*)(ws + TOPKV_OFF);
  int*   listt = (int*)(ws + LISTT_OFF);
  float* listw = (float*)(ws + LISTW_OFF);
  int*   listf = (int*)(ws + LISTF_OFF);
  int*   selt  = (int*)(ws + SELT_OFF);
  float* selw  = (float*)(ws + SELW_OFF);
  float* imp   = (float*)(ws + IMP_OFF);
  int*   cnt   = (int*)(ws + CNT_OFF);
  int*   nsel  = (int*)(ws + NSEL_OFF);
  f16*   w1t_all = (f16*)(ws + W1TA_OFF);
  f16*   w2t_all = (f16*)(ws + W2TA_OFF);
  f16*   hbuf_all = (f16*)(ws + HA_OFF);
  f16*   ye    = (f16*)(ws + YE_OFF);
  int*   tokmap = (int*)(ws + TOKMAP_OFF);
  const char* zbuf = ws + ZERO_OFF;

  hipMemsetAsync(ws, 0, 8192, stream);

  gate_kernel<<<S_TOK/4, 256, 0, stream>>>(x, Wg, probs, tki, tkv, xf16);
  imp_kernel<<<NEXP, 256, 0, stream>>>(probs, imp);
  compact_kernel<<<SK/256, 256, 0, stream>>>(tki, tkv, cnt, listt, listw, listf, tokmap);
  select_kernel<<<NEXP, 1024, 0, stream>>>(listt, listw, listf, cnt, selt, selw, nsel, imp,
                                           out + (size_t)S_TOK*DMODEL);
  buildmap_kernel<<<NEXP*CAP/256, 256, 0, stream>>>(selt, tki, tokmap);

  tcvt64_kernel<<<dim3(HDIM/64, DMODEL/64, NEXP), 256, 0, stream>>>(W1, w1t_all, DMODEL, HDIM);
  tcvt64_kernel<<<dim3(DMODEL/64, HDIM/64, NEXP), 256, 0, stream>>>(W2, w2t_all, HDIM, DMODEL);
  gemm1_4w<<<NEXP*160, 256, 0, stream>>>(xf16, w1t_all, selt, nsel, hbuf_all, zbuf);
  gemm2_8p<<<NEXP*80, 512, 0, stream>>>(hbuf_all, w2t_all, selw, nsel, ye);
  combine2_kernel<<<S_TOK, 256, 0, stream>>>(ye, tokmap, out);
}

// Round 17
// 562.777 us; speedup vs baseline: 1.0696x; 1.0696x over previous
//
#include <hip/hip_runtime.h>
#include <hip/hip_fp16.h>
#include <math.h>

#define S_TOK 8192
#define DMODEL 1024
#define HDIM 4096
#define NEXP 8
#define KTOP2 2
#define CAP 2560
#define SK (S_TOK*KTOP2)

typedef _Float16 f16;
typedef _Float16 f16x8 __attribute__((ext_vector_type(8)));
typedef float f32x4 __attribute__((ext_vector_type(4)));

typedef const __attribute__((address_space(1))) void* gas_cp;
typedef __attribute__((address_space(3))) void* las_p;

__device__ __forceinline__ void gload16(const void* g, void* l) {
  __builtin_amdgcn_global_load_lds((gas_cp)g, (las_p)l, 16, 0, 0);
}

// ---------------- ws layout (bytes) ----------------
static const size_t ZERO_OFF  = 0;          // 4096 zeroed every call
static const size_t IMP_OFF   = 4096;
static const size_t CNT_OFF   = 4160;
static const size_t NSEL_OFF  = 4224;
static const size_t PROBS_OFF = 8192;
static const size_t TOPKI_OFF = 270336;
static const size_t TOPKV_OFF = 335872;
static const size_t LISTT_OFF = 401408;
static const size_t LISTW_OFF = 663552;
static const size_t LISTF_OFF = 925696;     // dead after select -> reused for tokmap
static const size_t SELT_OFF  = 1187840;
static const size_t SELW_OFF  = 1269760;
static const size_t XF16_OFF  = 1351680;                                  // S*D f16 = 16MB
static const size_t W1TA_OFF  = 18128896;                                 // 8*H*D f16 = 64MB
static const size_t W2TA_OFF  = W1TA_OFF + (size_t)NEXP*HDIM*DMODEL*2;
static const size_t HA_OFF    = W2TA_OFF + (size_t)NEXP*DMODEL*HDIM*2;    // 8*CAP*H f16 = 160MB
static const size_t YE_OFF    = XF16_OFF;   // 40MB aliased over xf16/w1t (dead by gemm2)
static const size_t TOKMAP_OFF = LISTF_OFF;

// ---------------- fast erf-based gelu (A&S 7.1.26, |err|<1.5e-7) ----------------
__device__ __forceinline__ float fast_gelu(float v) {
  float av = fabsf(v);
  float z  = av * 0.70710678118654752f;
  float tt = __builtin_amdgcn_rcpf(1.0f + 0.3275911f*z);
  float poly = tt*(0.254829592f + tt*(-0.284496736f + tt*(1.421413741f + tt*(-1.453152027f + tt*1.061405429f))));
  float ee = 1.0f - poly*__expf(-z*z);       // erf(z) for z>=0
  return 0.5f*(v + v*copysignf(ee, v));      // 0.5*v*(1+erf(v/sqrt2))
}

// ---------------- gate (fused: also emits x as f16) ----------------
__global__ __launch_bounds__(256) void gate_kernel(const float* __restrict__ x, const float* __restrict__ Wg,
                                                   float* __restrict__ probs, int* __restrict__ tki,
                                                   float* __restrict__ tkv, f16* __restrict__ xf) {
  int lane = threadIdx.x & 63;
  int t = blockIdx.x*4 + (threadIdx.x >> 6);
  const float* xr = x + (size_t)t*DMODEL;
  f16* xw = xf + (size_t)t*DMODEL;
  float p[NEXP];
  #pragma unroll
  for (int e=0;e<NEXP;e++) p[e] = 0.f;
  #pragma unroll
  for (int it=0; it<4; ++it) {
    int d0 = it*256 + lane*4;
    float4 xv = *(const float4*)(xr + d0);
    union { f16 h[4]; short4 s4; } o;
    o.h[0]=(f16)xv.x; o.h[1]=(f16)xv.y; o.h[2]=(f16)xv.z; o.h[3]=(f16)xv.w;
    *(short4*)(xw + d0) = o.s4;
    #pragma unroll
    for (int c=0;c<4;c++) {
      float xs = (c==0)?xv.x:(c==1)?xv.y:(c==2)?xv.z:xv.w;
      const float4* wg = (const float4*)(Wg + (size_t)(d0+c)*NEXP);
      float4 w0 = wg[0], w1 = wg[1];
      p[0]+=xs*w0.x; p[1]+=xs*w0.y; p[2]+=xs*w0.z; p[3]+=xs*w0.w;
      p[4]+=xs*w1.x; p[5]+=xs*w1.y; p[6]+=xs*w1.z; p[7]+=xs*w1.w;
    }
  }
  #pragma unroll
  for (int off=32; off; off>>=1) {
    #pragma unroll
    for (int e=0;e<NEXP;e++) p[e] += __shfl_xor(p[e], off);
  }
  float mx = p[0];
  #pragma unroll
  for (int e=1;e<NEXP;e++) mx = fmaxf(mx, p[e]);
  float sum = 0.f;
  #pragma unroll
  for (int e=0;e<NEXP;e++) { p[e] = expf(p[e]-mx); sum += p[e]; }
  float inv = 1.f/sum;
  #pragma unroll
  for (int e=0;e<NEXP;e++) p[e] *= inv;
  if (lane == 0) {
    ((float4*)(probs + t*NEXP))[0] = make_float4(p[0],p[1],p[2],p[3]);
    ((float4*)(probs + t*NEXP))[1] = make_float4(p[4],p[5],p[6],p[7]);
    int i1 = 0; float v1 = p[0];
    #pragma unroll
    for (int e=1;e<NEXP;e++) if (p[e] > v1) { v1 = p[e]; i1 = e; }
    int i2 = -1; float v2 = -1.f;
    #pragma unroll
    for (int e=0;e<NEXP;e++) if (e != i1 && p[e] > v2) { v2 = p[e]; i2 = e; }
    tki[t*2] = i1; tki[t*2+1] = i2;
    tkv[t*2] = v1; tkv[t*2+1] = v2;
  }
}

// ---------------- importance ----------------
__global__ __launch_bounds__(256) void imp_kernel(const float* __restrict__ probs, float* __restrict__ imp) {
  int e = blockIdx.x;
  float s = 0.f;
  for (int t = threadIdx.x; t < S_TOK; t += 256) s += probs[t*NEXP + e];
  #pragma unroll
  for (int off=32; off; off>>=1) s += __shfl_xor(s, off);
  __shared__ float red[4];
  if ((threadIdx.x & 63) == 0) red[threadIdx.x>>6] = s;
  __syncthreads();
  if (threadIdx.x == 0) imp[e] = red[0]+red[1]+red[2]+red[3];
}

// ---------------- compact (+ tokmap init: grid is exactly SK threads) ----------------
__global__ __launch_bounds__(256) void compact_kernel(const int* __restrict__ tki, const float* __restrict__ tkv,
                                                      int* __restrict__ cnt, int* __restrict__ listt,
                                                      float* __restrict__ listw, int* __restrict__ listf,
                                                      int* __restrict__ tokmap) {
  int i = blockIdx.x*256 + threadIdx.x;
  tokmap[i] = -1;
  int e = tki[i];
  int p = atomicAdd(&cnt[e], 1);
  listt[e*S_TOK + p] = i >> 1;
  listw[e*S_TOK + p] = tkv[i];
  listf[e*S_TOK + p] = i;
}

// ---------------- capacity selection (+ fused aux-loss: imp,cnt stream-complete) ----------------
__global__ __launch_bounds__(1024) void select_kernel(const int* __restrict__ listt, const float* __restrict__ listw,
                                                      const int* __restrict__ listf, const int* __restrict__ cnt,
                                                      int* __restrict__ selt, float* __restrict__ selw,
                                                      int* __restrict__ nsel, const float* __restrict__ imp,
                                                      float* __restrict__ aux_out) {
  __shared__ float kw[8192];
  __shared__ unsigned short kf[8192];
  int e = blockIdx.x;
  int n = cnt[e];
  const int* lt = listt + e*S_TOK; const float* lw = listw + e*S_TOK; const int* lf = listf + e*S_TOK;
  int* st = selt + e*CAP; float* sw = selw + e*CAP;
  if (threadIdx.x == 0) nsel[e] = (n < CAP) ? n : CAP;
  if (e == 0 && threadIdx.x == 1) {
    float a = 0.f;
    #pragma unroll
    for (int q=0;q<NEXP;q++) a += imp[q] * (float)cnt[q];
    *aux_out = a * (8.0f / 67108864.0f);
  }
  if (n <= CAP) {
    for (int i = threadIdx.x; i < CAP; i += 1024) {
      if (i < n) { st[i] = lt[i]; sw[i] = lw[i]; }
      else       { st[i] = -1;    sw[i] = 0.f;  }
    }
  } else {
    for (int i = threadIdx.x; i < n; i += 1024) { kw[i] = lw[i]; kf[i] = (unsigned short)lf[i]; }
    __syncthreads();
    for (int i = threadIdx.x; i < n; i += 1024) {
      float wi = kw[i]; int fi = kf[i];
      int rank = 0;
      for (int j = 0; j < n; ++j) {
        float wj = kw[j];
        rank += (wj > wi) || (wj == wi && (int)kf[j] < fi);
      }
      if (rank < CAP) { st[rank] = lt[i]; sw[rank] = wi; }
    }
  }
}

// ---------------- tokmap ----------------
__global__ __launch_bounds__(256) void buildmap_kernel(const int* __restrict__ selt, const int* __restrict__ tki,
                                                       int* __restrict__ tokmap) {
  int i = blockIdx.x*256 + threadIdx.x;
  int t = selt[i];
  if (t >= 0) {
    int e = i / CAP;
    int k = (tki[2*t] == e) ? 0 : 1;
    tokmap[2*t + k] = i;
  }
}

// ---------------- combine ----------------
__global__ __launch_bounds__(256) void combine2_kernel(const f16* __restrict__ ye, const int* __restrict__ tokmap,
                                                       float* __restrict__ out) {
  int t = blockIdx.x;
  int c = threadIdx.x * 4;
  int i0 = tokmap[2*t], i1 = tokmap[2*t+1];
  float4 o = {0.f, 0.f, 0.f, 0.f};
  if (i0 >= 0) {
    union { short4 s; f16 h[4]; } v;
    v.s = *(const short4*)(ye + (size_t)i0*DMODEL + c);
    o.x += (float)v.h[0]; o.y += (float)v.h[1]; o.z += (float)v.h[2]; o.w += (float)v.h[3];
  }
  if (i1 >= 0) {
    union { short4 s; f16 h[4]; } v;
    v.s = *(const short4*)(ye + (size_t)i1*DMODEL + c);
    o.x += (float)v.h[0]; o.y += (float)v.h[1]; o.z += (float)v.h[2]; o.w += (float)v.h[3];
  }
  *(float4*)(out + (size_t)t*DMODEL + c) = o;
}

// ---------------- transpose + cvt, 64x64 tiles ----------------
__global__ __launch_bounds__(256) void tcvt64_kernel(const float* __restrict__ src0, f16* __restrict__ dst0,
                                                     int R, int C) {
  __shared__ float tile[64][65];
  const float* src = src0 + (size_t)blockIdx.z*R*C;
  f16* dst = dst0 + (size_t)blockIdx.z*R*C;
  int c0 = blockIdx.x*64, r0 = blockIdx.y*64;
  int tr = threadIdx.x >> 4;
  int tc = threadIdx.x & 15;
  #pragma unroll
  for (int j=0;j<4;j++) {
    int r = tr + 16*j;
    float4 v = *(const float4*)(src + (size_t)(r0+r)*C + c0 + tc*4);
    tile[r][tc*4+0]=v.x; tile[r][tc*4+1]=v.y; tile[r][tc*4+2]=v.z; tile[r][tc*4+3]=v.w;
  }
  __syncthreads();
  #pragma unroll
  for (int j=0;j<4;j++) {
    int c = tr + 16*j;
    union { f16 h[4]; short4 s; } o;
    #pragma unroll
    for (int i=0;i<4;i++) o.h[i] = (f16)tile[tc*4+i][c];
    *(short4*)(dst + (size_t)(c0+c)*R + r0 + tc*4) = o.s;
  }
}

#define BAR()   asm volatile("s_barrier" ::: "memory")
#define VMW(n)  asm volatile("s_waitcnt vmcnt(" #n ")" ::: "memory")
#define LGKM0() asm volatile("s_waitcnt lgkmcnt(0)" ::: "memory")
#define LGKM8() asm volatile("s_waitcnt lgkmcnt(8)" ::: "memory")
#define PRIO1() __builtin_amdgcn_s_setprio(1)
#define PRIO0() __builtin_amdgcn_s_setprio(0)

// ================= GEMM1: m201-style 8-phase 256x256, BK=64 (r13/r15-exact, proven 230us) =================
__global__ __launch_bounds__(512, 2) void gemm1_8p(const f16* __restrict__ xf, const f16* __restrict__ w1t_all,
                                                   const int* __restrict__ selt_all, const int* __restrict__ nsel_all,
                                                   f16* __restrict__ hbuf_all, const char* __restrict__ zbuf) {
  int bid = blockIdx.x;
  int wid = (bid & 7)*160 + (bid >> 3);      // XCD = expert
  int e = wid / 160; int rem = wid % 160;    // 160 = 8 supercols x (10 m x 2 n)
  int sc = rem / 20;
  int lm = (rem % 20) >> 1, ln = rem & 1;
  int m0 = lm * 256;
  int n0 = (sc*2 + ln) * 256;
  int nsel = nsel_all[e];
  if (m0 >= nsel) return;
  const int* selt = selt_all + e*CAP;
  const f16* w1t = w1t_all + (size_t)e*HDIM*DMODEL;
  f16* hbuf = hbuf_all + (size_t)e*CAP*HDIM;

  __shared__ __align__(16) char lds[131072];
  char* ldsA = lds;
  char* ldsB = lds + 65536;

  int tid = threadIdx.x;
  int l = tid & 63, w = tid >> 6;
  int wr = w >> 2, wc = w & 3;
  int fr = l & 15, kq = l >> 4;

  int srow = tid >> 3;
  int sswz = ((tid & 7) ^ (srow & 7)) * 16;
  const char* sA[2][2];
  const char* sB[2][2];
  #pragma unroll
  for (int h=0;h<2;h++)
    #pragma unroll
    for (int s=0;s<2;s++) {
      int R = h*128 + s*64 + srow;
      int t0 = selt[m0 + R];
      sA[h][s] = ((t0>=0) ? (const char*)(xf + (size_t)t0*DMODEL) : zbuf) + sswz;
      sB[h][s] = (const char*)(w1t + (size_t)(n0 + R)*DMODEL) + sswz;
    }
  int dst = tid*16;

  #define STG_A(buf,h,s,t) gload16(sA[h][s] + (t)*128, ldsA + (buf)*32768 + (h)*16384 + (s)*8192 + dst)
  #define STG_B(buf,h,s,t) gload16(sB[h][s] + (t)*128, ldsB + (buf)*32768 + (h)*16384 + (s)*8192 + dst)

  int slotk0 = ((kq)   ^ (fr&7))*16;
  int slotk1 = ((4+kq) ^ (fr&7))*16;
  int aBase = wr*16384 + fr*128;
  int bBase = (wc>>1)*16384 + ((wc&1)*64 + fr)*128;

  f16x8 aR[4][2], bL[2][2], bH[2][2];
  f32x4 acc[8][4];
  #pragma unroll
  for (int m=0;m<8;m++)
    #pragma unroll
    for (int n=0;n<4;n++) acc[m][n] = (f32x4){0.f,0.f,0.f,0.f};

  #define RD_A(buf, mq) { \
    _Pragma("unroll") for (int mm=0;mm<4;mm++) { \
      aR[mm][0] = *(const f16x8*)(ldsA + (buf)*32768 + aBase + ((mq)*4+mm)*2048 + slotk0); \
      aR[mm][1] = *(const f16x8*)(ldsA + (buf)*32768 + aBase + ((mq)*4+mm)*2048 + slotk1); } }
  #define RD_B(buf, nq, BR) { \
    _Pragma("unroll") for (int nn=0;nn<2;nn++) { \
      BR[nn][0] = *(const f16x8*)(ldsB + (buf)*32768 + bBase + ((nq)*2+nn)*2048 + slotk0); \
      BR[nn][1] = *(const f16x8*)(ldsB + (buf)*32768 + bBase + ((nq)*2+nn)*2048 + slotk1); } }
  #define MM(mq, nq, BR) { \
    _Pragma("unroll") for (int ks=0;ks<2;ks++) \
      _Pragma("unroll") for (int mm=0;mm<4;mm++) \
        _Pragma("unroll") for (int nn=0;nn<2;nn++) \
          acc[(mq)*4+mm][(nq)*2+nn] = __builtin_amdgcn_mfma_f32_16x16x32_f16(aR[mm][ks], BR[nn][ks], acc[(mq)*4+mm][(nq)*2+nn], 0,0,0); }

  STG_A(0,0,0,0); STG_A(0,1,0,0); STG_A(0,0,1,0); STG_A(0,1,1,0);
  STG_B(0,0,0,0); STG_B(0,0,1,0); STG_B(0,1,0,0); STG_B(0,1,1,0);
  STG_A(1,0,0,1); STG_A(1,1,0,1);
  STG_B(1,0,0,1); STG_B(1,0,1,1); STG_B(1,1,0,1); STG_B(1,1,1,1);
  VMW(6); BAR();

  const int NT = DMODEL/64;   // 16 K-tiles, 8 iters
  for (int j = 0; j < NT/2; ++j) {
    int t1 = 2*j+1, st0 = 2*j+2, st1 = 2*j+3;
    int g0 = (st0 < NT), g1 = (st1 < NT);
    RD_A(0,0); RD_B(0,0,bL);
    STG_A(1,0,1,t1); STG_A(1,1,1,t1);
    LGKM8();
    BAR(); LGKM0(); PRIO1(); MM(0,0,bL); PRIO0(); BAR();
    RD_B(0,1,bH);
    if (g0) { STG_A(0,0,0,st0); STG_A(0,1,0,st0); }
    BAR(); LGKM0(); PRIO1(); MM(0,1,bH); PRIO0(); BAR();
    RD_A(0,1);
    if (g0) { STG_B(0,0,0,st0); STG_B(0,0,1,st0); }
    BAR(); LGKM0(); PRIO1(); MM(1,0,bL); PRIO0(); BAR();
    if (g0) { STG_B(0,1,0,st0); STG_B(0,1,1,st0); }
    BAR(); PRIO1(); MM(1,1,bH); PRIO0();
    if (g0) { VMW(6); } else { VMW(0); }
    BAR();
    RD_A(1,0); RD_B(1,0,bL);
    if (g0) { STG_A(0,0,1,st0); STG_A(0,1,1,st0); }
    LGKM8();
    BAR(); LGKM0(); PRIO1(); MM(0,0,bL); PRIO0(); BAR();
    RD_B(1,1,bH);
    if (g1) { STG_A(1,0,0,st1); STG_A(1,1,0,st1); }
    BAR(); LGKM0(); PRIO1(); MM(0,1,bH); PRIO0(); BAR();
    RD_A(1,1);
    if (g1) { STG_B(1,0,0,st1); STG_B(1,0,1,st1); }
    BAR(); LGKM0(); PRIO1(); MM(1,0,bL); PRIO0(); BAR();
    if (g1) { STG_B(1,1,0,st1); STG_B(1,1,1,st1); }
    BAR(); PRIO1(); MM(1,1,bH); PRIO0();
    if (g1) { VMW(6); } else { VMW(0); }
    BAR();
  }
  #undef STG_A
  #undef STG_B
  #undef RD_A
  #undef RD_B
  #undef MM

  int rowb = m0 + wr*128;
  int colb = n0 + wc*64;
  #pragma unroll
  for (int m=0;m<8;m++) {
    #pragma unroll
    for (int n=0;n<4;n++) {
      #pragma unroll
      for (int r=0;r<4;r++) {
        int row = rowb + m*16 + kq*4 + r;
        int col = colb + n*16 + fr;
        hbuf[(size_t)row*HDIM + col] = (f16)fast_gelu(acc[m][n][r]);
      }
    }
  }
}

// ================= GEMM2: 8-phase-family 256x128, BK=64, K=4096 (r13, proven) =================
__global__ __launch_bounds__(512, 2) void gemm2_8p(const f16* __restrict__ hbuf_all, const f16* __restrict__ w2t_all,
                                                   const float* __restrict__ selw_all, const int* __restrict__ nsel_all,
                                                   f16* __restrict__ ye) {
  int bid = blockIdx.x;
  int wid = (bid & 7)*80 + (bid >> 3);       // XCD = expert; 80 = 10m x 8n
  int e = wid / 80; int rem = wid % 80;
  int lm = rem >> 3, ln = rem & 7;
  int m0 = lm * 256;
  int n0 = ln * 128;
  int nsel = nsel_all[e];
  if (m0 >= nsel) return;
  const f16* hb  = hbuf_all + (size_t)e*CAP*HDIM;
  const f16* w2t = w2t_all + (size_t)e*DMODEL*HDIM;

  __shared__ __align__(16) char lds[98304];
  char* ldsA = lds;            // 2 x 32KB
  char* ldsB = lds + 65536;    // 2 x 16KB

  int tid = threadIdx.x;
  int l = tid & 63, w = tid >> 6;
  int wr = w >> 2, wc = w & 3;
  int fr = l & 15, kq = l >> 4;

  int srow = tid >> 3;
  int sswz = ((tid & 7) ^ (srow & 7)) * 16;
  const char* sA[2][2];
  const char* sB[2];
  #pragma unroll
  for (int h=0;h<2;h++)
    #pragma unroll
    for (int s=0;s<2;s++)
      sA[h][s] = (const char*)(hb + (size_t)(m0 + h*128 + s*64 + srow)*HDIM) + sswz;
  #pragma unroll
  for (int s=0;s<2;s++)
    sB[s] = (const char*)(w2t + (size_t)(n0 + s*64 + srow)*HDIM) + sswz;
  int dst = tid*16;

  #define STG2_A(buf,h,s,t) gload16(sA[h][s] + (t)*128, ldsA + (buf)*32768 + (h)*16384 + (s)*8192 + dst)
  #define STG2_B(buf,s,t)   gload16(sB[s] + (t)*128, ldsB + (buf)*16384 + (s)*8192 + dst)

  int slotk0 = ((kq)   ^ (fr&7))*16;
  int slotk1 = ((4+kq) ^ (fr&7))*16;
  int aBase = wr*16384 + fr*128;
  int bBase = (wc>>1)*8192 + ((wc&1)*32 + fr)*128;

  f16x8 aR[4][2], bF[2][2];
  f32x4 acc[8][2];
  #pragma unroll
  for (int m=0;m<8;m++)
    #pragma unroll
    for (int n=0;n<2;n++) acc[m][n] = (f32x4){0.f,0.f,0.f,0.f};

  #define RD2_A(buf, mq) { \
    _Pragma("unroll") for (int mm=0;mm<4;mm++) { \
      aR[mm][0] = *(const f16x8*)(ldsA + (buf)*32768 + aBase + ((mq)*4+mm)*2048 + slotk0); \
      aR[mm][1] = *(const f16x8*)(ldsA + (buf)*32768 + aBase + ((mq)*4+mm)*2048 + slotk1); } }
  #define RD2_B(buf) { \
    _Pragma("unroll") for (int nn=0;nn<2;nn++) { \
      bF[nn][0] = *(const f16x8*)(ldsB + (buf)*16384 + bBase + nn*2048 + slotk0); \
      bF[nn][1] = *(const f16x8*)(ldsB + (buf)*16384 + bBase + nn*2048 + slotk1); } }
  #define MM2(mq) { \
    _Pragma("unroll") for (int ks=0;ks<2;ks++) \
      _Pragma("unroll") for (int mm=0;mm<4;mm++) \
        _Pragma("unroll") for (int nn=0;nn<2;nn++) \
          acc[(mq)*4+mm][nn] = __builtin_amdgcn_mfma_f32_16x16x32_f16(aR[mm][ks], bF[nn][ks], acc[(mq)*4+mm][nn], 0,0,0); }

  STG2_A(0,0,0,0); STG2_A(0,0,1,0); STG2_A(0,1,0,0); STG2_A(0,1,1,0);
  STG2_B(0,0,0); STG2_B(0,1,0);
  STG2_A(1,0,0,1); STG2_A(1,1,0,1);
  STG2_B(1,0,1); STG2_B(1,1,1);
  VMW(4); BAR();

  const int NT = HDIM/64;   // 64 K-tiles, 32 iters
  for (int j = 0; j < NT/2; ++j) {
    int t1 = 2*j+1, st0 = 2*j+2, st1 = 2*j+3;
    int g0 = (st0 < NT), g1 = (st1 < NT);
    RD2_A(0,0); RD2_B(0);
    STG2_A(1,0,1,t1); STG2_A(1,1,1,t1);
    LGKM8();
    BAR(); LGKM0(); PRIO1(); MM2(0); PRIO0(); BAR();
    RD2_A(0,1);
    if (g0) { STG2_A(0,0,0,st0); STG2_A(0,1,0,st0); STG2_B(0,0,st0); STG2_B(0,1,st0); }
    BAR(); LGKM0(); PRIO1(); MM2(1); PRIO0();
    if (g0) { VMW(4); } else { VMW(0); }
    BAR();
    RD2_A(1,0); RD2_B(1);
    if (g0) { STG2_A(0,0,1,st0); STG2_A(0,1,1,st0); }
    LGKM8();
    BAR(); LGKM0(); PRIO1(); MM2(0); PRIO0(); BAR();
    RD2_A(1,1);
    if (g1) { STG2_A(1,0,0,st1); STG2_A(1,1,0,st1); STG2_B(1,0,st1); STG2_B(1,1,st1); }
    BAR(); LGKM0(); PRIO1(); MM2(1); PRIO0();
    if (g1) { VMW(4); } else { VMW(0); }
    BAR();
  }
  #undef STG2_A
  #undef STG2_B
  #undef RD2_A
  #undef RD2_B
  #undef MM2

  int rowb = m0 + wr*128;
  int colb = n0 + wc*32;
  #pragma unroll
  for (int m=0;m<8;m++) {
    #pragma unroll
    for (int r=0;r<4;r++) {
      int row = rowb + m*16 + kq*4 + r;
      float wg = selw_all[e*CAP + row];
      f16* yr = ye + (size_t)(e*CAP + row)*DMODEL;
      #pragma unroll
      for (int n=0;n<2;n++) {
        int col = colb + n*16 + fr;
        yr[col] = (f16)(acc[m][n][r] * wg);
      }
    }
  }
}

// ---------------- launch ----------------
extern "C" void kernel_launch(void* const* d_in, const int* in_sizes, int n_in,
                              void* d_out, int out_size, void* d_ws, size_t ws_size,
                              hipStream_t stream) {
  const float* x  = (const float*)d_in[0];
  const float* Wg = (const float*)d_in[1];
  const float* W1 = (const float*)d_in[2];
  const float* W2 = (const float*)d_in[3];
  float* out = (float*)d_out;

  char* ws = (char*)d_ws;
  f16*   xf16  = (f16*)(ws + XF16_OFF);
  float* probs = (float*)(ws + PROBS_OFF);
  int*   tki   = (int*)(ws + TOPKI_OFF);
  float* tkv   = (float*)(ws + TOPKV_OFF);
  int*   listt = (int*)(ws + LISTT_OFF);
  float* listw = (float*)(ws + LISTW_OFF);
  int*   listf = (int*)(ws + LISTF_OFF);
  int*   selt  = (int*)(ws + SELT_OFF);
  float* selw  = (float*)(ws + SELW_OFF);
  float* imp   = (float*)(ws + IMP_OFF);
  int*   cnt   = (int*)(ws + CNT_OFF);
  int*   nsel  = (int*)(ws + NSEL_OFF);
  f16*   w1t_all = (f16*)(ws + W1TA_OFF);
  f16*   w2t_all = (f16*)(ws + W2TA_OFF);
  f16*   hbuf_all = (f16*)(ws + HA_OFF);
  f16*   ye    = (f16*)(ws + YE_OFF);
  int*   tokmap = (int*)(ws + TOKMAP_OFF);
  const char* zbuf = ws + ZERO_OFF;

  hipMemsetAsync(ws, 0, 8192, stream);

  gate_kernel<<<S_TOK/4, 256, 0, stream>>>(x, Wg, probs, tki, tkv, xf16);
  imp_kernel<<<NEXP, 256, 0, stream>>>(probs, imp);
  compact_kernel<<<SK/256, 256, 0, stream>>>(tki, tkv, cnt, listt, listw, listf, tokmap);
  select_kernel<<<NEXP, 1024, 0, stream>>>(listt, listw, listf, cnt, selt, selw, nsel, imp,
                                           out + (size_t)S_TOK*DMODEL);
  buildmap_kernel<<<NEXP*CAP/256, 256, 0, stream>>>(selt, tki, tokmap);

  tcvt64_kernel<<<dim3(HDIM/64, DMODEL/64, NEXP), 256, 0, stream>>>(W1, w1t_all, DMODEL, HDIM);
  tcvt64_kernel<<<dim3(DMODEL/64, HDIM/64, NEXP), 256, 0, stream>>>(W2, w2t_all, HDIM, DMODEL);
  gemm1_8p<<<NEXP*160, 512, 0, stream>>>(xf16, w1t_all, selt, nsel, hbuf_all, zbuf);
  gemm2_8p<<<NEXP*80, 512, 0, stream>>>(hbuf_all, w2t_all, selw, nsel, ye);
  combine2_kernel<<<S_TOK, 256, 0, stream>>>(ye, tokmap, out);
}